// Round 4
// baseline (44.051 us; speedup 1.0000x reference)
//
#include <hip/hip_runtime.h>

// LinearAutoDecoder: rgb[n, j] = dot(X[n, 0:63],  W_pos[3*cid[n]+j, :]) +
//                                dot(X[n, 63:127], W_feat[3*cid[n]+j, :])
//
// One wave (64 lanes) per point, FOUR points in flight per iteration (MLP to
// cover the cid->weight->FMA dependent chain, ~500cy). Lane i covers
// pos-feature i (i<63; xa zeroed on lane 63) and latent-feature i (all 64).
// n is wave-uniform -> all loads are SGPR-base + hoisted VGPR lane offset.
// Reduction is pure-VALU DPP (rocPRIM ladder), result valid in lane 63.

constexpr int ROWW = 127;   // 63 pos + 64 latent

template <int CTRL, int RMASK, int BMASK>
__device__ __forceinline__ float dpp_add(float x) {
    int t = __builtin_amdgcn_update_dpp(0, __builtin_bit_cast(int, x),
                                        CTRL, RMASK, BMASK, false);
    return x + __builtin_bit_cast(float, t);
}

// Full-wave64 sum; valid in lane 63. rocPRIM-style DPP ladder.
__device__ __forceinline__ float wave_sum63(float x) {
    x = dpp_add<0xB1,  0xF, 0xF>(x);  // quad_perm [1,0,3,2]  (xor 1)
    x = dpp_add<0x4E,  0xF, 0xF>(x);  // quad_perm [2,3,0,1]  (xor 2)
    x = dpp_add<0x114, 0xF, 0xE>(x);  // row_shr:4
    x = dpp_add<0x118, 0xF, 0xC>(x);  // row_shr:8
    x = dpp_add<0x142, 0xA, 0xF>(x);  // row_bcast:15
    x = dpp_add<0x143, 0xC, 0xF>(x);  // row_bcast:31
    return x;
}

__global__ __launch_bounds__(256, 8) void lad_kernel(
    const float* __restrict__ X,
    const int*   __restrict__ cid,
    const float* __restrict__ Wp,   // [768][63]
    const float* __restrict__ Wf,   // [768][64]
    float*       __restrict__ out,  // [N][3]
    int npts)
{
    const int lane  = threadIdx.x & 63;
    const int wid   = (blockIdx.x * blockDim.x + threadIdx.x) >> 6;
    const int nW    = (gridDim.x * blockDim.x) >> 6;
    const int lanec = (lane < 63) ? lane : 62;   // clamped pos index (avoids OOB)
    const bool l63  = (lane == 63);

    for (int n = wid; n < npts; n += 4 * nW) {
        int   np[4]; bool has[4];
        float xa[4], xb[4]; int c[4];

        // ---- batch all X / cid loads (16 + 4 loads in flight) ----
        #pragma unroll
        for (int p = 0; p < 4; ++p) {
            np[p]  = n + p * nW;
            has[p] = np[p] < npts;
            const int ns = has[p] ? np[p] : n;    // clamp OOB to a valid row
            const float* xp = X + (size_t)ns * ROWW;
            xa[p] = xp[lane];        // pos feature `lane` (lane 63: zeroed below)
            xb[p] = xp[63 + lane];   // latent feature `lane` (all 64 valid)
            c[p]  = __builtin_amdgcn_readfirstlane(cid[ns]);
        }
        if (l63) { xa[0] = 0.0f; xa[1] = 0.0f; xa[2] = 0.0f; xa[3] = 0.0f; }

        // ---- batch all 24 weight loads + FMAs ----
        float a[4][3];
        #pragma unroll
        for (int p = 0; p < 4; ++p) {
            const float* wp = Wp + (size_t)(3 * c[p]) * 63;
            const float* wf = Wf + (size_t)(3 * c[p]) * 64;
            a[p][0] = fmaf(xa[p], wp[lanec],       xb[p] * wf[lane]);
            a[p][1] = fmaf(xa[p], wp[63 + lanec],  xb[p] * wf[64 + lane]);
            a[p][2] = fmaf(xa[p], wp[126 + lanec], xb[p] * wf[128 + lane]);
        }

        // ---- 12 independent DPP reduction chains (pure VALU, no DS) ----
        #pragma unroll
        for (int p = 0; p < 4; ++p) {
            a[p][0] = wave_sum63(a[p][0]);
            a[p][1] = wave_sum63(a[p][1]);
            a[p][2] = wave_sum63(a[p][2]);
        }

        if (l63) {
            #pragma unroll
            for (int p = 0; p < 4; ++p) {
                if (has[p]) {
                    float* o = out + 3 * (size_t)np[p];
                    o[0] = a[p][0]; o[1] = a[p][1]; o[2] = a[p][2];
                }
            }
        }
    }
}

extern "C" void kernel_launch(void* const* d_in, const int* in_sizes, int n_in,
                              void* d_out, int out_size, void* d_ws, size_t ws_size,
                              hipStream_t stream) {
    const float* X   = (const float*)d_in[0];
    const int*   cid = (const int*)d_in[1];
    const float* Wp  = (const float*)d_in[2];
    const float* Wf  = (const float*)d_in[3];
    float* out = (float*)d_out;
    const int npts = in_sizes[1];   // cluster_ids element count == N

    dim3 grid(2048), block(256);
    hipLaunchKernelGGL(lad_kernel, grid, block, 0, stream,
                       X, cid, Wp, Wf, out, npts);
}